// Round 7
// baseline (122.848 us; speedup 1.0000x reference)
//
#include <hip/hip_runtime.h>
#include <hip/hip_bf16.h>

// Non-backtracking random walk, 32 steps.
// out = [walks (steps+1,n) ; walk_edges (steps,n)] int32.
//
// R7: clean test of 4 chains/thread x L2-fitting table (R5 conflated 4-chain
// with 64B rows -> thrash; R6 conflated revert with a prefetch that cost
// +11us). Layout: 32B u16 rows (3.2MB, two rows/64B line, chosen+alt always
// ONE line) + 200KB hi-bit array (hot, resident). 4 chains/thread -> ~16
// independent line-gathers in flight per wave at each chain stall. Choices
// preloaded in 16-step halves (64 independent coalesced nt loads) so a
// choices miss never serializes with a table miss. Nontemporal loads/stores
// for all streaming traffic so it doesn't evict the table from L2.
// Pack kernel verifies uniform CSR (deg==16, offset==16v, ids<2^17); on
// violation walker takes a fully-general fallback.

#define DEG 16
#define CHAINS 4

__global__ void pack_check_kernel(const int* __restrict__ adj_nodes,
                                  const int* __restrict__ adj_offset,
                                  const int* __restrict__ degrees,
                                  int n,
                                  unsigned int* __restrict__ lo32,   // 8 u32 per row (32B)
                                  unsigned short* __restrict__ hi,   // hbits per node
                                  int* __restrict__ flag) {
    int v = blockIdx.x * blockDim.x + threadIdx.x;
    if (v >= n) return;

    bool bad = (degrees[v] != DEG) || (adj_offset[v] != v * DEG);

    const uint4* row4 = (const uint4*)(adj_nodes + (size_t)v * DEG); // 64B-aligned
    uint4 r[4];
    r[0] = row4[0]; r[1] = row4[1]; r[2] = row4[2]; r[3] = row4[3];
    const unsigned* rr = (const unsigned*)r;

    union { unsigned u32[8]; uint4 v4[2]; } p;
    unsigned hbits = 0;
#pragma unroll
    for (int j = 0; j < 8; ++j) {
        unsigned u0 = rr[2 * j];
        unsigned u1 = rr[2 * j + 1];
        if (u0 >= 131072u || u1 >= 131072u) bad = true;   // needs >17 bits
        p.u32[j] = (u0 & 0xffffu) | ((u1 & 0xffffu) << 16);
        hbits |= ((u0 >> 16) & 1u) << (2 * j);
        hbits |= ((u1 >> 16) & 1u) << (2 * j + 1);
    }
    uint4* dst = (uint4*)(lo32 + (size_t)v * 8);          // 32B row
    dst[0] = p.v4[0];
    dst[1] = p.v4[1];
    hi[v] = (unsigned short)hbits;

    if (bad) atomicOr(flag, 1);
}

template <int STEPS>
__global__ __launch_bounds__(64) void walker_fast4(
    const unsigned short* __restrict__ pk,   // 16 u16 per row (32B stride)
    const unsigned short* __restrict__ hi,   // hbits per node
    const int* __restrict__ choices,
    int* __restrict__ out, int n, int h,
    const int* __restrict__ flag,
    const int* __restrict__ adj_nodes,
    const int* __restrict__ adj_offset,
    const int* __restrict__ degrees) {

    int t = blockIdx.x * blockDim.x + threadIdx.x;
    if (t >= h) return;

    int* walks      = out;                    // [STEPS+1, n]
    int* walk_edges = out + (STEPS + 1) * n;  // [STEPS, n]

    int  w[CHAINS], wsx[CHAINS];
    bool val[CHAINS];
#pragma unroll
    for (int c = 0; c < CHAINS; ++c) {
        w[c]   = t + c * h;
        val[c] = (w[c] < n);
        wsx[c] = val[c] ? w[c] : t;           // safe index for loads
        if (val[c]) __builtin_nontemporal_store(w[c], &walks[w[c]]);
    }

    if (*flag == 0) {
        // ---- fast path: uniform CSR deg=16, 32B rows, 4 chains/thread ----
        int prev[CHAINS], cur[CHAINS];
#pragma unroll
        for (int c = 0; c < CHAINS; ++c) { prev[c] = -1; cur[c] = wsx[c]; }

        static_assert(STEPS % 16 == 0, "");
#pragma unroll 1
        for (int half = 0; half < STEPS / 16; ++half) {
            // preload this half's choices: 64 independent coalesced loads
            int ch[CHAINS][16];
#pragma unroll
            for (int i = 0; i < 16; ++i)
#pragma unroll
                for (int c = 0; c < CHAINS; ++c)
                    ch[c][i] = __builtin_nontemporal_load(
                        &choices[(half * 16 + i) * n + wsx[c]]);

#pragma unroll
            for (int i = 0; i < 16; ++i) {
                int step = half * 16 + i;
                unsigned e[CHAINS], ae[CHAINS], l0[CHAINS], l1[CHAINS], hb[CHAINS];
#pragma unroll
                for (int c = 0; c < CHAINS; ++c) {
                    int chv = ch[c][i];
                    e[c]  = chv & (DEG - 1);
                    ae[c] = (e[c] + 1 + chv % (DEG - 1)) & (DEG - 1);
                    const unsigned short* r = pk + (unsigned)cur[c] * 16u;
                    l0[c] = r[e[c]];      // chosen+alt: same 64B line always
                    l1[c] = r[ae[c]];
                    hb[c] = hi[cur[c]];   // hot 200KB array
                }
#pragma unroll
                for (int c = 0; c < CHAINS; ++c) {
                    int n0 = (int)(l0[c] | (((hb[c] >> e[c])  & 1u) << 16));
                    int n1 = (int)(l1[c] | (((hb[c] >> ae[c]) & 1u) << 16));
                    bool bt = (n0 == prev[c]);
                    int nw  = bt ? n1 : n0;
                    int ce  = (cur[c] << 4) + (int)(bt ? ae[c] : e[c]);
                    if (val[c]) {
                        __builtin_nontemporal_store(nw, &walks[(step + 1) * n + w[c]]);
                        __builtin_nontemporal_store(ce, &walk_edges[step * n + w[c]]);
                    }
                    prev[c] = cur[c];
                    cur[c]  = nw;
                }
            }
        }
    } else {
        // ---- general fallback ----
        for (int c = 0; c < CHAINS; ++c) {
            if (!val[c]) continue;
            int wk = w[c];
            int prev = -1, cur = wk;
            for (int i = 0; i < STEPS; ++i) {
                int chv = choices[i * n + wk];
                int deg = degrees[cur];
                int off = adj_offset[cur];
                int nb  = deg - 1 > 1 ? deg - 1 : 1;

                int ee     = chv % deg;
                int chosen = off + ee;
                int alt    = off + (ee + 1 + chv % nb) % deg;

                int nv0 = adj_nodes[chosen];
                int nv1 = adj_nodes[alt];

                bool bt = (nv0 == prev);
                int nw  = bt ? nv1 : nv0;
                walks[(i + 1) * n + wk] = nw;
                walk_edges[i * n + wk]  = bt ? alt : chosen;
                prev = cur;
                cur  = nw;
            }
        }
    }
}

__global__ __launch_bounds__(256) void walker_generic(
    const int* __restrict__ adj_nodes,
    const int* __restrict__ adj_offset,
    const int* __restrict__ degrees,
    const int* __restrict__ choices,
    int* __restrict__ out, int n, int steps) {

    int w = blockIdx.x * blockDim.x + threadIdx.x;
    if (w >= n) return;

    int* walks      = out;
    int* walk_edges = out + (steps + 1) * n;
    walks[w] = w;

    int prev = -1, cur = w;
    for (int i = 0; i < steps; ++i) {
        int chv = choices[i * n + w];
        int deg = degrees[cur];
        int off = adj_offset[cur];
        int nb  = deg - 1 > 1 ? deg - 1 : 1;

        int e      = chv % deg;
        int chosen = off + e;
        int alt    = off + (e + 1 + chv % nb) % deg;

        int nv0 = adj_nodes[chosen];
        int nv1 = adj_nodes[alt];

        bool bt = (nv0 == prev);
        int nw  = bt ? nv1 : nv0;
        walks[(i + 1) * n + w] = nw;
        walk_edges[i * n + w]  = bt ? alt : chosen;
        prev = cur;
        cur  = nw;
    }
}

extern "C" void kernel_launch(void* const* d_in, const int* in_sizes, int n_in,
                              void* d_out, int out_size, void* d_ws, size_t ws_size,
                              hipStream_t stream) {
    // inputs: 0=x (unused), 1=adj_nodes, 2=adj_offset, 3=degrees, 4=choices
    const int* adj_nodes  = (const int*)d_in[1];
    const int* adj_offset = (const int*)d_in[2];
    const int* degrees    = (const int*)d_in[3];
    const int* choices    = (const int*)d_in[4];
    int* out = (int*)d_out;

    int n     = in_sizes[2];
    int steps = in_sizes[4] / n;

    // ws layout: [0,4) flag | [64, 64+32n) lo rows | aligned hi u16[n]
    size_t lo_off = 64;
    size_t lo_bytes = (size_t)n * 32;
    size_t hi_off = lo_off + ((lo_bytes + 63) & ~(size_t)63);
    size_t need   = hi_off + (size_t)n * 2;

    if (steps == 32 && ws_size >= need) {
        int* flag = (int*)d_ws;
        unsigned int*   lo32 = (unsigned int*)((char*)d_ws + lo_off);
        unsigned short* pk   = (unsigned short*)lo32;
        unsigned short* hi   = (unsigned short*)((char*)d_ws + hi_off);

        hipMemsetAsync(flag, 0, sizeof(int), stream);
        int pb = 256, pg = (n + pb - 1) / pb;
        pack_check_kernel<<<pg, pb, 0, stream>>>(adj_nodes, adj_offset, degrees,
                                                 n, lo32, hi, flag);
        int h  = (n + CHAINS - 1) / CHAINS;
        int wb = 64, wg = (h + wb - 1) / wb;
        walker_fast4<32><<<wg, wb, 0, stream>>>(pk, hi, choices, out, n, h, flag,
                                                adj_nodes, adj_offset, degrees);
    } else {
        int block = 256, grid = (n + block - 1) / block;
        walker_generic<<<grid, block, 0, stream>>>(adj_nodes, adj_offset,
                                                   degrees, choices, out, n, steps);
    }
}

// Round 10
// 106.266 us; speedup vs baseline: 1.1560x; 1.1560x over previous
//
#include <hip/hip_runtime.h>
#include <hip/hip_bf16.h>

// Non-backtracking random walk, 32 steps.
// out = [walks (steps+1,n) ; walk_edges (steps,n)] int32.
//
// R8 (2nd resubmit after two infra failures; code unchanged): walker is
// gather-REQUEST-throughput bound (~2400cyc/step vs ~400 pure latency;
// ~14 req/cyc/XCD-L2). Config = R4's best (stride-18 u16 rows with in-row
// hbits, 2 chains/thread, 782 waves) + PREDICATED alt-load: only
// backtracking lanes (P=1/16, ~2-4 lanes/wave) issue the alt gather ->
// unconditional gathers per step drop 3->2 (-31% lane-requests). hbits at
// r[16] shares the chosen-entry's cache line most rows -> MSHR-merged.
// Pack kernel verifies uniform CSR (deg==16, offset==16v, ids<2^17); on
// violation walker takes a fully-general fallback.

#define DEG 16
#define CHAINS 2

__global__ void pack_check_kernel(const int* __restrict__ adj_nodes,
                                  const int* __restrict__ adj_offset,
                                  const int* __restrict__ degrees,
                                  int n,
                                  unsigned int* __restrict__ pk32,  // 9 u32 per row (36B)
                                  int* __restrict__ flag) {
    int v = blockIdx.x * blockDim.x + threadIdx.x;
    if (v >= n) return;

    bool bad = (degrees[v] != DEG) || (adj_offset[v] != v * DEG);

    const uint4* row4 = (const uint4*)(adj_nodes + (size_t)v * DEG); // 64B-aligned
    uint4 r[4];
    r[0] = row4[0]; r[1] = row4[1]; r[2] = row4[2]; r[3] = row4[3];
    const unsigned* rr = (const unsigned*)r;

    unsigned wv[8];
    unsigned hbits = 0;
#pragma unroll
    for (int j = 0; j < 8; ++j) {
        unsigned u0 = rr[2 * j];
        unsigned u1 = rr[2 * j + 1];
        if (u0 >= 131072u || u1 >= 131072u) bad = true;   // needs >17 bits
        wv[j] = (u0 & 0xffffu) | ((u1 & 0xffffu) << 16);
        hbits |= ((u0 >> 16) & 1u) << (2 * j);
        hbits |= ((u1 >> 16) & 1u) << (2 * j + 1);
    }
    unsigned int* dst = pk32 + (size_t)v * 9;   // 36B/row, 4B-aligned
#pragma unroll
    for (int j = 0; j < 8; ++j) dst[j] = wv[j];
    dst[8] = hbits;                              // u16 hbits at r[16]

    if (bad) atomicOr(flag, 1);
}

template <int STEPS>
__global__ __launch_bounds__(64) void walker_fast2(
    const unsigned short* __restrict__ pk,   // stride-18 u16 rows
    const int* __restrict__ choices,
    int* __restrict__ out, int n, int h,
    const int* __restrict__ flag,
    const int* __restrict__ adj_nodes,
    const int* __restrict__ adj_offset,
    const int* __restrict__ degrees) {

    int t = blockIdx.x * blockDim.x + threadIdx.x;
    if (t >= h) return;

    int* walks      = out;                    // [STEPS+1, n]
    int* walk_edges = out + (STEPS + 1) * n;  // [STEPS, n]

    int w0 = t;
    int w1 = t + h;
    bool has1 = (w1 < n);
    int w1s = has1 ? w1 : w0;

    __builtin_nontemporal_store(w0, &walks[w0]);
    if (has1) __builtin_nontemporal_store(w1, &walks[w1]);

    if (*flag == 0) {
        // ---- fast path: uniform CSR deg=16, 2 chains, predicated alt ----
        int c0[STEPS], c1[STEPS];
#pragma unroll
        for (int i = 0; i < STEPS; ++i) {
            c0[i] = __builtin_nontemporal_load(&choices[i * n + w0]);
            c1[i] = __builtin_nontemporal_load(&choices[i * n + w1s]);
        }

        int prev0 = -1, cur0 = w0;
        int prev1 = -1, cur1 = w1s;
#pragma unroll
        for (int i = 0; i < STEPS; ++i) {
            unsigned ch0 = (unsigned)c0[i];
            unsigned ch1 = (unsigned)c1[i];
            unsigned e0 = ch0 & (DEG - 1);
            unsigned e1 = ch1 & (DEG - 1);

            const unsigned short* r0 = pk + (unsigned)cur0 * 18u;
            const unsigned short* r1 = pk + (unsigned)cur1 * 18u;

            // four unconditional loads (2 per chain), issued together
            unsigned l00 = r0[e0];
            unsigned hb0 = r0[16];
            unsigned l10 = r1[e1];
            unsigned hb1 = r1[16];

            int n00 = (int)(l00 | (((hb0 >> e0) & 1u) << 16));
            int n10 = (int)(l10 | (((hb1 >> e1) & 1u) << 16));

            int nw0 = n00, nw1 = n10;
            unsigned ef0 = e0, ef1 = e1;
            // predicated alt gathers: ~2-4 lanes/wave execute each
            if (n00 == prev0) {
                unsigned a0 = (e0 + 1u + ch0 % (DEG - 1)) & (DEG - 1);
                unsigned l01 = r0[a0];
                nw0 = (int)(l01 | (((hb0 >> a0) & 1u) << 16));
                ef0 = a0;
            }
            if (n10 == prev1) {
                unsigned a1 = (e1 + 1u + ch1 % (DEG - 1)) & (DEG - 1);
                unsigned l11 = r1[a1];
                nw1 = (int)(l11 | (((hb1 >> a1) & 1u) << 16));
                ef1 = a1;
            }

            int ce0 = (cur0 << 4) + (int)ef0;
            int ce1 = (cur1 << 4) + (int)ef1;

            __builtin_nontemporal_store(nw0, &walks[(i + 1) * n + w0]);
            __builtin_nontemporal_store(ce0, &walk_edges[i * n + w0]);
            if (has1) {
                __builtin_nontemporal_store(nw1, &walks[(i + 1) * n + w1]);
                __builtin_nontemporal_store(ce1, &walk_edges[i * n + w1]);
            }
            prev0 = cur0; cur0 = nw0;
            prev1 = cur1; cur1 = nw1;
        }
    } else {
        // ---- general fallback: 2 dependent gathers/step ----
        for (int k = 0; k < 2; ++k) {
            int w = (k == 0) ? w0 : w1;
            if (w >= n) break;
            int prev = -1, cur = w;
            for (int i = 0; i < STEPS; ++i) {
                int chv = choices[i * n + w];
                int deg = degrees[cur];
                int off = adj_offset[cur];
                int nb  = deg - 1 > 1 ? deg - 1 : 1;

                int e      = chv % deg;
                int chosen = off + e;
                int alt    = off + (e + 1 + chv % nb) % deg;

                int nv0 = adj_nodes[chosen];
                int nv1 = adj_nodes[alt];

                bool bt = (nv0 == prev);
                int nw  = bt ? nv1 : nv0;
                walks[(i + 1) * n + w] = nw;
                walk_edges[i * n + w]  = bt ? alt : chosen;
                prev = cur;
                cur  = nw;
            }
        }
    }
}

__global__ __launch_bounds__(256) void walker_generic(
    const int* __restrict__ adj_nodes,
    const int* __restrict__ adj_offset,
    const int* __restrict__ degrees,
    const int* __restrict__ choices,
    int* __restrict__ out, int n, int steps) {

    int w = blockIdx.x * blockDim.x + threadIdx.x;
    if (w >= n) return;

    int* walks      = out;
    int* walk_edges = out + (steps + 1) * n;
    walks[w] = w;

    int prev = -1, cur = w;
    for (int i = 0; i < steps; ++i) {
        int chv = choices[i * n + w];
        int deg = degrees[cur];
        int off = adj_offset[cur];
        int nb  = deg - 1 > 1 ? deg - 1 : 1;

        int e      = chv % deg;
        int chosen = off + e;
        int alt    = off + (e + 1 + chv % nb) % deg;

        int nv0 = adj_nodes[chosen];
        int nv1 = adj_nodes[alt];

        bool bt = (nv0 == prev);
        int nw  = bt ? nv1 : nv0;
        walks[(i + 1) * n + w] = nw;
        walk_edges[i * n + w]  = bt ? alt : chosen;
        prev = cur;
        cur  = nw;
    }
}

extern "C" void kernel_launch(void* const* d_in, const int* in_sizes, int n_in,
                              void* d_out, int out_size, void* d_ws, size_t ws_size,
                              hipStream_t stream) {
    // inputs: 0=x (unused), 1=adj_nodes, 2=adj_offset, 3=degrees, 4=choices
    const int* adj_nodes  = (const int*)d_in[1];
    const int* adj_offset = (const int*)d_in[2];
    const int* degrees    = (const int*)d_in[3];
    const int* choices    = (const int*)d_in[4];
    int* out = (int*)d_out;

    int n     = in_sizes[2];
    int steps = in_sizes[4] / n;

    // ws layout: [0,4) flag | [64, 64+36n) packed stride-18 rows
    size_t pk_off = 64;
    size_t need   = pk_off + (size_t)n * 36;

    if (steps == 32 && ws_size >= need) {
        int* flag = (int*)d_ws;
        unsigned int*   pk32 = (unsigned int*)((char*)d_ws + pk_off);
        unsigned short* pk   = (unsigned short*)pk32;

        hipMemsetAsync(flag, 0, sizeof(int), stream);
        int pb = 256, pg = (n + pb - 1) / pb;
        pack_check_kernel<<<pg, pb, 0, stream>>>(adj_nodes, adj_offset, degrees,
                                                 n, pk32, flag);
        int h  = (n + CHAINS - 1) / CHAINS;
        int wb = 64, wg = (h + wb - 1) / wb;
        walker_fast2<32><<<wg, wb, 0, stream>>>(pk, choices, out, n, h, flag,
                                                adj_nodes, adj_offset, degrees);
    } else {
        int block = 256, grid = (n + block - 1) / block;
        walker_generic<<<grid, block, 0, stream>>>(adj_nodes, adj_offset,
                                                   degrees, choices, out, n, steps);
    }
}